// Round 7
// baseline (253.445 us; speedup 1.0000x reference)
//
#include <hip/hip_runtime.h>

namespace {

constexpr int H = 224, W = 224, B = 4, S = 21, R = 5;
constexpr int HW = H * W;            // 50176

constexpr int TW = 32, TH = 8;       // output tile per block (256 threads)
constexpr int GX = W / TW;           // 7
constexpr int GY = H / TH;           // 28
constexpr int WINW = 40, WINH = 32;  // staged source window (fit proof: see r2/r3)
constexpr int LSTR = 41;             // float4 row stride: 164 dwords == 4 (mod 32)
constexpr int NPX = WINW * WINH;     // 1280 staged pixels; LDS = 32*41*16 B = 20.5 KiB

__constant__ float c_sin[5] = {-0.5000010604f, -0.2588196365f, 0.0f,
                                0.2588196365f,  0.5000010604f};
__constant__ float c_cos[5] = { 0.8660247916f,  0.9659256678f, 1.0f,
                                0.9659256678f,  0.8660247916f};

struct alignas(4) f3 { float x, y, z; };   // 12 B global-side pixel

typedef float f2v __attribute__((ext_vector_type(2)));  // native clang vector: nt-builtin-legal

__device__ __forceinline__ float vIn(int x) {   // H == W
    return ((unsigned)x < (unsigned)W) ? 1.0f : 0.0f;
}
__device__ __forceinline__ float cmp(const float4& v, int c) {  // folded under unroll
    return c == 0 ? v.x : (c == 1 ? v.y : v.z);
}

// Non-temporal 12-B pixel store: nt f2v + nt float (vec3 would pad to 16 B).
// nt skips L2 line allocation -> no read-for-ownership on the 253 MB output stream.
__device__ __forceinline__ void store_px_nt(float* p, float a0, float a1, float a2) {
    f2v v01; v01.x = a0; v01.y = a1;
    __builtin_nontemporal_store(v01, (f2v*)p);
    __builtin_nontemporal_store(a2, p + 2);
}

// One block = 32x8 output tile for fixed (b, r); all 21 shifts from a float4 LDS window.
// Register diet: pre-blend rows (x-group) / cols (y-group) once -> 24-float tiles.
__global__ __launch_bounds__(256, 4) void fused_shift_rotate_nt(
    const float* __restrict__ xs, float* __restrict__ out) {
    __shared__ float4 lds4[WINH][LSTR];
    const int tid = threadIdx.x;
    const int tile = blockIdx.x;
    const int tx0 = (tile % GX) * TW;
    const int ty0 = (tile / GX) * TH;
    const int b = blockIdx.y;
    const int r = blockIdx.z;

    const float sr = c_sin[r], cr = c_cos[r];
    const float cx = 0.5f * (W - 1);

    // ---- uniform source-window origin from tile-corner extremes
    const float dxs = (float)tx0 - cx, dxe = (float)(tx0 + TW - 1) - cx;
    const float dys = (float)ty0 - cx, dye = (float)(ty0 + TH - 1) - cx;
    const float ixmin = cx + dxs * cr + fminf(dys * sr, dye * sr);
    const float iymin = cx + fminf(-dxs * sr, -dxe * sr) + dys * cr;
    const int cmin = min(max((int)floorf(ixmin) - 3, 0), W - WINW);
    const int rmin = min(max((int)floorf(iymin) - 3, 0), H - WINH);

    // ---- stage window: coalesced f3 global reads -> one ds_write_b128 per pixel
    const float* img = xs + (size_t)b * (HW * 3);
    const float* gsrc = img + rmin * (W * 3) + cmin * 3;
    #pragma unroll
    for (int k = 0; k < NPX / 256; ++k) {   // 5 iterations
        int idx = tid + k * 256;
        int row = idx / WINW;               // magic-mul
        int col = idx - row * WINW;
        const f3 t = *(const f3*)(gsrc + row * (W * 3) + col * 3);
        lds4[row][col] = make_float4(t.x, t.y, t.z, 0.0f);
    }
    __syncthreads();

    // ---- per-thread rotation geometry (identical math to proven kernel)
    const int wpx = tx0 + (tid & (TW - 1));
    const int hpx = ty0 + (tid >> 5);
    const float dx = (float)wpx - cx;
    const float dy = (float)hpx - cx;
    const float ix = fmaf(dy, sr, fmaf(dx, cr, cx));
    const float iy = fmaf(dy, cr, fmaf(-dx, sr, cx));

    const float x0f = floorf(ix), y0f = floorf(iy);
    const int x0 = (int)x0f, y0 = (int)y0f;
    const float wx = ix - x0f, wy = iy - y0f;
    const float wxl = 1.0f - wx, wyl = 1.0f - wy;

    const float vx0 = vIn(x0), vx1 = vIn(x0 + 1);
    const float vy0 = vIn(y0), vy1 = vIn(y0 + 1);
    const float rwy0 = wyl * vy0, rwy1 = wy * vy1;   // stage-2 y weights (masked)
    const float cwx0 = wxl * vx0, cwx1 = wx * vx1;   // stage-2 x weights (masked)

    const int pix = hpx * W + wpx;
    float* obase = out + ((size_t)(r * S) * B + b) * (size_t)(HW * 3) + (size_t)pix * 3;
    constexpr size_t splane = (size_t)B * HW * 3;    // +1 in s

    auto lcol = [&](int g) { int l = g - cmin; return min(max(l, 0), WINW - 1); };
    auto lrow = [&](int g) { int l = g - rmin; return min(max(l, 0), WINH - 1); };

    const int xc0 = lcol(x0), xc1 = lcol(x0 + 1);

    // ---- x-shift group (s = 10..20): pre-blend rows y0/y0+1 once.
    // Rb[j][c] = rwy0*H[0][j][c] + rwy1*H[1][j][c]  (exact distributive rearrangement)
    {
        float Rb[8][3];
        const int R0 = lrow(y0), R1 = lrow(y0 + 1);
        #pragma unroll
        for (int j = 0; j < 8; ++j) {
            int xc = lcol(x0 - 3 + j);
            const float4 t0 = lds4[R0][xc];
            const float4 t1 = lds4[R1][xc];
            #pragma unroll
            for (int c = 0; c < 3; ++c)
                Rb[j][c] = rwy0 * cmp(t0, c) + rwy1 * cmp(t1, c);
        }
        constexpr int tx_tab[11] = {1, 2, 3, 4, 5, -1, -2, -3, -4, -5, 0};
        #pragma unroll
        for (int k = 0; k < 11; ++k) {
            const int tx = tx_tab[k];
            const int s = 10 + k;
            float a[3];
            if (tx & 1) {
                const int j = ((tx - 1) >> 1) + 3;       // compile-time
                int xb = x0 + ((tx - 1) >> 1);
                float cw0 = 0.5f * wxl * vx0 * vIn(xb);
                float cw1 = 0.5f * (wxl * vx0 + wx * vx1) * vIn(xb + 1);
                float cw2 = 0.5f * wx * vx1 * vIn(xb + 2);
                #pragma unroll
                for (int c = 0; c < 3; ++c)
                    a[c] = cw0 * Rb[j][c] + cw1 * Rb[j + 1][c] + cw2 * Rb[j + 2][c];
            } else {
                const int sx = tx >> 1;
                const int j = sx + 3;                    // compile-time
                float ax0 = cwx0 * vIn(x0 + sx);
                float ax1 = cwx1 * vIn(x0 + 1 + sx);
                #pragma unroll
                for (int c = 0; c < 3; ++c)
                    a[c] = ax0 * Rb[j][c] + ax1 * Rb[j + 1][c];
            }
            store_px_nt(obase + (size_t)s * splane, a[0], a[1], a[2]);
        }
    }

    // ---- y-shift group (s = 0..9): pre-blend cols x0/x0+1 once.
    // Cb[i][c] = cwx0*V[i][0][c] + cwx1*V[i][1][c]
    {
        float Cb[8][3];
        #pragma unroll
        for (int i = 0; i < 8; ++i) {
            const int RR = lrow(y0 - 3 + i);
            const float4 t0 = lds4[RR][xc0];
            const float4 t1 = lds4[RR][xc1];
            #pragma unroll
            for (int c = 0; c < 3; ++c)
                Cb[i][c] = cwx0 * cmp(t0, c) + cwx1 * cmp(t1, c);
        }
        constexpr int ty_tab[10] = {1, 2, 3, 4, 5, -1, -2, -3, -4, -5};
        #pragma unroll
        for (int k = 0; k < 10; ++k) {
            const int ty = ty_tab[k];
            const int s = k;
            float a[3];
            if (ty & 1) {
                const int i = ((ty - 1) >> 1) + 3;       // compile-time
                int yb = y0 + ((ty - 1) >> 1);
                float rw0 = 0.5f * wyl * vy0 * vIn(yb);
                float rw1 = 0.5f * (wyl * vy0 + wy * vy1) * vIn(yb + 1);
                float rw2 = 0.5f * wy * vy1 * vIn(yb + 2);
                #pragma unroll
                for (int c = 0; c < 3; ++c)
                    a[c] = rw0 * Cb[i][c] + rw1 * Cb[i + 1][c] + rw2 * Cb[i + 2][c];
            } else {
                const int sy = ty >> 1;
                const int i = sy + 3;                    // compile-time
                float ay0 = rwy0 * vIn(y0 + sy);
                float ay1 = rwy1 * vIn(y0 + 1 + sy);
                #pragma unroll
                for (int c = 0; c < 3; ++c)
                    a[c] = ay0 * Cb[i][c] + ay1 * Cb[i + 1][c];
            }
            store_px_nt(obase + (size_t)s * splane, a[0], a[1], a[2]);
        }
    }
}

} // namespace

extern "C" void kernel_launch(void* const* d_in, const int* in_sizes, int n_in,
                              void* d_out, int out_size, void* d_ws, size_t ws_size,
                              hipStream_t stream) {
    const float* xs = (const float*)d_in[0];
    float* out = (float*)d_out;
    dim3 grid(GX * GY, B, R);
    fused_shift_rotate_nt<<<grid, dim3(256), 0, stream>>>(xs, out);
}